// Round 1
// baseline (375.135 us; speedup 1.0000x reference)
//
#include <hip/hip_runtime.h>
#include <stdint.h>

// NeuralMemory (Titans-style) for MI355X / gfx950.
// Pipeline:
//  0. transpose+bf16-convert big weights (w_kv, w_q, w_combine) and mem_w0/w1
//  1. norms: ss=rmsnorm(seq,g_store), sr=rmsnorm(seq,g_ret), lr, gate (per token)
//  2. chunkgates: cmean -> mom_gate, 1-decay (per chunk)
//  3. GEMM: kv = ss @ w_kv ; q = sr @ w_q (bf16 MFMA, K=1024)
//  4. grad_kernel: per-chunk MLP grads -> surprise S (f32)
//  5. scan: momentum+updates linear recurrences over 64 chunks (in-place on S)
//  6. retrieve: per-chunk q@(w0+u0) -> silu -> @(w1+u1) -> rmsnorm*gamma*gate
//  7. GEMM: out = vals @ w_combine (f32 out; shift-by-63 via natural indexing)

#define SEQ 4096
#define NTOK 8192

typedef unsigned short u16;
typedef __attribute__((ext_vector_type(8))) short short8;
typedef __attribute__((ext_vector_type(4))) float f32x4;

__device__ __forceinline__ u16 f2b(float f) {
  union { float f; uint32_t u; } c; c.f = f;
  uint32_t u = c.u;
  uint32_t r = (u + 0x7fffu + ((u >> 16) & 1u)) >> 16;
  return (u16)r;
}
__device__ __forceinline__ float b2f(u16 h) {
  union { uint32_t u; float f; } c; c.u = ((uint32_t)h) << 16;
  return c.f;
}
__device__ __forceinline__ float sigm(float x) { return 1.f / (1.f + __expf(-x)); }

// XOR-swizzled element index inside a [rows][128] bf16 LDS tile (16B-granule swizzle)
__device__ __forceinline__ int sidx(int r, int c) {
  return r*128 + ((((c>>3) ^ (r&7))<<3) | (c&7));
}
// contiguous 8-bf16 fragment: rows vary per l15 (passed in row), k = ks*32 + l4*8
__device__ __forceinline__ short8 frag_row_lds128(const u16* buf, int row, int ks, int l4) {
  int g = ks*4 + l4;
  return *(const short8*)&buf[row*128 + ((g ^ (row&7))<<3)];
}
// gathered fragment: element i at (row = k0+l4*8+i, col = c)  [transposed operand]
__device__ __forceinline__ short8 frag_col_lds128(const u16* buf, int k0, int c, int l4) {
  short8 r;
  int cg = c>>3, co = c&7;
  int kb = k0 + l4*8;
#pragma unroll
  for (int i=0;i<8;++i) {
    int rr = kb + i;
    r[i] = (short)buf[rr*128 + (((cg ^ (rr&7))<<3) | co)];
  }
  return r;
}

// ---------------- weight prep ----------------

// src: R x C f32  ->  dst: C x R bf16 (transposed)
__global__ __launch_bounds__(256) void transpose_bf16(
    const float* __restrict__ src, u16* __restrict__ dst, int R, int C)
{
  __shared__ u16 tile[64*66];
  int tiles_x = C >> 6;
  int tx = blockIdx.x % tiles_x, ty = blockIdx.x / tiles_x;
  int c0 = tx*64, r0 = ty*64;
#pragma unroll
  for (int it=0; it<16; ++it) {
    int idx = it*256 + threadIdx.x;
    int rr = idx>>6, cc = idx&63;
    tile[cc*66 + rr] = f2b(src[(size_t)(r0+rr)*C + c0+cc]);
  }
  __syncthreads();
#pragma unroll
  for (int it=0; it<16; ++it) {
    int idx = it*256 + threadIdx.x;
    int rr = idx>>6, cc = idx&63;
    dst[(size_t)(c0+rr)*R + r0+cc] = tile[rr*66 + cc];
  }
}

__global__ __launch_bounds__(256) void smallprep(
    const float* __restrict__ w0, const float* __restrict__ w1,
    u16* __restrict__ w0b, u16* __restrict__ w0T,
    u16* __restrict__ w1b, u16* __restrict__ w1T)
{
  int id = blockIdx.x*256 + threadIdx.x;   // 0..16383
  int i = id>>7, j = id&127;
  float a = w0[id], b = w1[id];
  w0b[id] = f2b(a); w1b[id] = f2b(b);
  w0T[j*128+i] = f2b(a); w1T[j*128+i] = f2b(b);
}

// ---------------- norms + per-token gates ----------------

__global__ __launch_bounds__(256) void norms_kernel(
    const float* __restrict__ seq, const float* __restrict__ gs,
    const float* __restrict__ gr, const float* __restrict__ wstep,
    const float* __restrict__ wgate, u16* __restrict__ ss,
    u16* __restrict__ sr, float* __restrict__ lr, float* __restrict__ gate)
{
  int t = blockIdx.x; int b = t>>12, pos = t&4095;
  int tid = threadIdx.x;
  const float* row = seq + (size_t)t*1024;
  float x[4]; float ssq = 0.f;
#pragma unroll
  for (int i=0;i<4;++i){ x[i]=row[i*256+tid]; ssq += x[i]*x[i]; }
  for (int m=32;m;m>>=1) ssq += __shfl_xor(ssq, m);
  __shared__ float red[4];
  __shared__ float r2[4][16];
  int wv = tid>>6;
  if ((tid&63)==0) red[wv] = ssq;
  __syncthreads();
  float tot = red[0]+red[1]+red[2]+red[3];
  float inv = rsqrtf(tot*(1.f/1024.f) + 1e-6f);
  float ps[8], pg[8];
#pragma unroll
  for (int h=0;h<8;++h){ ps[h]=0.f; pg[h]=0.f; }
#pragma unroll
  for (int i=0;i<4;++i) {
    int d = i*256+tid;
    float sv = x[i]*inv*gs[d];
    float rv = x[i]*inv*gr[d];
    ss[(size_t)t*1024+d] = f2b(sv);
    sr[(size_t)t*1024+d] = f2b(rv);
#pragma unroll
    for (int h=0;h<8;++h) { ps[h] += sv*wstep[d*8+h]; pg[h] += rv*wgate[d*8+h]; }
  }
#pragma unroll
  for (int h=0;h<8;++h)
    for (int m=32;m;m>>=1){ ps[h] += __shfl_xor(ps[h],m); pg[h] += __shfl_xor(pg[h],m); }
  if ((tid&63)==0) {
#pragma unroll
    for (int h=0;h<8;++h){ r2[wv][h]=ps[h]; r2[wv][8+h]=pg[h]; }
  }
  __syncthreads();
  if (tid < 16) {
    float s = r2[0][tid]+r2[1][tid]+r2[2][tid]+r2[3][tid];
    float sg = sigm(s);
    if (tid<8) lr[((size_t)(b*8+tid))*4096 + pos] = sg*0.01f;
    else gate[((size_t)(b*8+(tid-8)))*4096 + pos] = sg;
  }
}

// ---------------- per-chunk gates from cmean ----------------

__global__ __launch_bounds__(256) void chunkgates_kernel(
    const u16* __restrict__ ss, const float* __restrict__ wmom,
    const float* __restrict__ wdec, float* __restrict__ mg,
    float* __restrict__ d1m)
{
  int bc = blockIdx.x; int b = bc>>6, ch = bc&63;
  size_t t0 = (size_t)(b*4096 + ch*64)*1024;
  int tid = threadIdx.x;
  float cm[4]; cm[0]=cm[1]=cm[2]=cm[3]=0.f;
  for (int tok=0; tok<64; ++tok) {
#pragma unroll
    for (int i=0;i<4;++i)
      cm[i] += b2f(ss[t0 + (size_t)tok*1024 + i*256 + tid]);
  }
  float pm[8], pd[8];
#pragma unroll
  for (int h=0;h<8;++h){ pm[h]=0.f; pd[h]=0.f; }
#pragma unroll
  for (int i=0;i<4;++i) {
    float v = cm[i]*(1.f/64.f);
    int d = i*256+tid;
#pragma unroll
    for (int h=0;h<8;++h){ pm[h]+=v*wmom[d*8+h]; pd[h]+=v*wdec[d*8+h]; }
  }
#pragma unroll
  for (int h=0;h<8;++h)
    for (int m=32;m;m>>=1){ pm[h] += __shfl_xor(pm[h],m); pd[h] += __shfl_xor(pd[h],m); }
  __shared__ float r2[4][16];
  int wv = tid>>6;
  if ((tid&63)==0) {
#pragma unroll
    for (int h=0;h<8;++h){ r2[wv][h]=pm[h]; r2[wv][8+h]=pd[h]; }
  }
  __syncthreads();
  if (tid < 16) {
    float s = r2[0][tid]+r2[1][tid]+r2[2][tid]+r2[3][tid];
    if (tid<8) mg[(b*8+tid)*64 + ch] = sigm(s);
    else d1m[(b*8+(tid-8))*64 + ch] = 1.f - sigm(s);
  }
}

// ---------------- generic bf16 GEMM: C = A(MxK) @ Bt(NxK)^T ----------------

__global__ __launch_bounds__(256) void gemm_bt(
    const u16* __restrict__ A, const u16* __restrict__ Bt,
    void* __restrict__ C, int M, int N, int K, int out_f32)
{
  __shared__ __align__(16) u16 As[128*64];
  __shared__ __align__(16) u16 Bs[128*64];
  int tid = threadIdx.x;
  int wv = tid>>6, lane = tid&63;
  int wr = wv>>1, wc = wv&1;
  int l15 = lane&15, l4 = lane>>4;
  int brow = blockIdx.y*128, bcol = blockIdx.x*128;
  f32x4 acc[4][4] = {};
  for (int kt=0; kt<K; kt+=64) {
#pragma unroll
    for (int it=0; it<4; ++it) {
      int gi = it*256 + tid;
      int row = gi>>3, g = gi&7;
      int sg = g ^ (row&7);
      *(short8*)&As[row*64 + sg*8] = *(const short8*)&A[(size_t)(brow+row)*K + kt + g*8];
      *(short8*)&Bs[row*64 + sg*8] = *(const short8*)&Bt[(size_t)(bcol+row)*K + kt + g*8];
    }
    __syncthreads();
#pragma unroll
    for (int ks=0; ks<2; ++ks) {
      short8 af[4], bfr[4];
#pragma unroll
      for (int m=0;m<4;++m) {
        int row = wr*64 + m*16 + l15;
        int g = ks*4 + l4;
        af[m] = *(const short8*)&As[row*64 + ((g ^ (row&7))<<3)];
      }
#pragma unroll
      for (int n=0;n<4;++n) {
        int row = wc*64 + n*16 + l15;
        int g = ks*4 + l4;
        bfr[n] = *(const short8*)&Bs[row*64 + ((g ^ (row&7))<<3)];
      }
#pragma unroll
      for (int m=0;m<4;++m)
#pragma unroll
        for (int n=0;n<4;++n)
          acc[m][n] = __builtin_amdgcn_mfma_f32_16x16x32_bf16(af[m], bfr[n], acc[m][n], 0,0,0);
    }
    __syncthreads();
  }
#pragma unroll
  for (int m=0;m<4;++m) {
#pragma unroll
    for (int n=0;n<4;++n) {
      int col = bcol + wc*64 + n*16 + l15;
#pragma unroll
      for (int j=0;j<4;++j) {
        int row = brow + wr*64 + m*16 + l4*4 + j;
        if (out_f32) ((float*)C)[(size_t)row*N + col] = acc[m][n][j];
        else ((u16*)C)[(size_t)row*N + col] = f2b(acc[m][n][j]);
      }
    }
  }
}

// ---------------- per-chunk MLP gradients (surprise) ----------------
// loss = sum_r lr[r] * mean_e (pred[r,e]-v[r,e])^2 ; pred = silu(k@w0)@w1
// S0 = -dL/dw0 = -k^T @ dx1 ; S1 = -dL/dw1 = -a^T @ dpred

__global__ __launch_bounds__(256) void grad_kernel(
    const u16* __restrict__ kvout, const float* __restrict__ lr,
    const u16* __restrict__ w0T, const u16* __restrict__ w1T,
    const u16* __restrict__ w1b, float* __restrict__ S)
{
  __shared__ __align__(16) u16 Kt[64*128];
  __shared__ __align__(16) u16 Vt[64*128];
  __shared__ __align__(16) u16 Al[64*128];
  __shared__ __align__(16) u16 Dl[64*128];
  __shared__ __align__(16) u16 DXl[64*128];
  __shared__ float lr_s[64];
  int bid = blockIdx.x;
  int bh = bid>>6, ch = bid&63;
  int b = bh>>3, h = bh&7;
  int tid = threadIdx.x;
  int w = tid>>6, lane = tid&63;
  int l15 = lane&15, l4 = lane>>4;
  size_t t0 = (size_t)(b*4096 + ch*64);

#pragma unroll
  for (int it=0; it<4; ++it) {
    int gi = it*256 + tid;
    int row = gi>>4, g = gi&15;
    int sg = g ^ (row&7);
    *(short8*)&Kt[row*128 + sg*8] = *(const short8*)&kvout[(t0+row)*2048 + h*128 + g*8];
    *(short8*)&Vt[row*128 + sg*8] = *(const short8*)&kvout[(t0+row)*2048 + 1024 + h*128 + g*8];
  }
  if (tid < 64) lr_s[tid] = lr[(size_t)bh*4096 + ch*64 + tid];
  __syncthreads();

  // x1 = k @ w0   (wave w owns rows [w*16, w*16+16))
  f32x4 x1[8] = {};
#pragma unroll
  for (int ks=0; ks<4; ++ks) {
    short8 af = frag_row_lds128(Kt, w*16 + l15, ks, l4);
    int kof = ks*32 + l4*8;
#pragma unroll
    for (int n=0;n<8;++n) {
      short8 bf = *(const short8*)&w0T[(size_t)(n*16+l15)*128 + kof];
      x1[n] = __builtin_amdgcn_mfma_f32_16x16x32_bf16(af, bf, x1[n], 0,0,0);
    }
  }
  // a = silu(x1) -> Al (keep x1 in regs for dsilu)
#pragma unroll
  for (int n=0;n<8;++n)
#pragma unroll
    for (int j=0;j<4;++j) {
      int r = w*16 + l4*4 + j, c = n*16 + l15;
      float xv = x1[n][j];
      Al[sidx(r,c)] = f2b(xv * sigm(xv));
    }
  // pred = a @ w1
  f32x4 pr[8] = {};
#pragma unroll
  for (int ks=0; ks<4; ++ks) {
    short8 af = frag_row_lds128(Al, w*16 + l15, ks, l4);
    int kof = ks*32 + l4*8;
#pragma unroll
    for (int n=0;n<8;++n) {
      short8 bf = *(const short8*)&w1T[(size_t)(n*16+l15)*128 + kof];
      pr[n] = __builtin_amdgcn_mfma_f32_16x16x32_bf16(af, bf, pr[n], 0,0,0);
    }
  }
  // dpred = (2/128)*lr*(pred - v) -> Dl
#pragma unroll
  for (int n=0;n<8;++n)
#pragma unroll
    for (int j=0;j<4;++j) {
      int r = w*16 + l4*4 + j, c = n*16 + l15;
      float dp = 0.015625f * lr_s[r] * (pr[n][j] - b2f(Vt[sidx(r,c)]));
      Dl[sidx(r,c)] = f2b(dp);
    }
  // da = dpred @ w1^T   (Bt form of w1^T is w1 row-major)
  f32x4 da[8] = {};
#pragma unroll
  for (int ks=0; ks<4; ++ks) {
    short8 af = frag_row_lds128(Dl, w*16 + l15, ks, l4);
    int kof = ks*32 + l4*8;
#pragma unroll
    for (int n=0;n<8;++n) {
      short8 bf = *(const short8*)&w1b[(size_t)(n*16+l15)*128 + kof];
      da[n] = __builtin_amdgcn_mfma_f32_16x16x32_bf16(af, bf, da[n], 0,0,0);
    }
  }
  // dx1 = da * silu'(x1) -> DXl
#pragma unroll
  for (int n=0;n<8;++n)
#pragma unroll
    for (int j=0;j<4;++j) {
      int r = w*16 + l4*4 + j, c = n*16 + l15;
      float xv = x1[n][j];
      float sg = sigm(xv);
      float dsl = sg*(1.f + xv*(1.f - sg));
      DXl[sidx(r,c)] = f2b(da[n][j]*dsl);
    }
  __syncthreads();

  // gw1 = a^T @ dpred -> S1 = -gw1   (wave w owns rows [w*32, w*32+32))
  float* S1 = S + ((size_t)(16+bh)*64 + ch)*16384;
  float* S0 = S + ((size_t)bh*64 + ch)*16384;
  {
    f32x4 g1[2][8] = {};
#pragma unroll
    for (int ks=0; ks<2; ++ks) {
      short8 af[2];
#pragma unroll
      for (int mi=0; mi<2; ++mi)
        af[mi] = frag_col_lds128(Al, ks*32, w*32 + mi*16 + l15, l4);
#pragma unroll
      for (int n=0;n<8;++n) {
        short8 bf = frag_col_lds128(Dl, ks*32, n*16 + l15, l4);
#pragma unroll
        for (int mi=0;mi<2;++mi)
          g1[mi][n] = __builtin_amdgcn_mfma_f32_16x16x32_bf16(af[mi], bf, g1[mi][n], 0,0,0);
      }
    }
#pragma unroll
    for (int mi=0;mi<2;++mi)
#pragma unroll
      for (int n=0;n<8;++n)
#pragma unroll
        for (int j=0;j<4;++j) {
          int r = w*32 + mi*16 + l4*4 + j, c = n*16 + l15;
          S1[r*128 + c] = -g1[mi][n][j];
        }
  }
  // gw0 = k^T @ dx1 -> S0 = -gw0
  {
    f32x4 g0[2][8] = {};
#pragma unroll
    for (int ks=0; ks<2; ++ks) {
      short8 af[2];
#pragma unroll
      for (int mi=0; mi<2; ++mi)
        af[mi] = frag_col_lds128(Kt, ks*32, w*32 + mi*16 + l15, l4);
#pragma unroll
      for (int n=0;n<8;++n) {
        short8 bf = frag_col_lds128(DXl, ks*32, n*16 + l15, l4);
#pragma unroll
        for (int mi=0;mi<2;++mi)
          g0[mi][n] = __builtin_amdgcn_mfma_f32_16x16x32_bf16(af[mi], bf, g0[mi][n], 0,0,0);
      }
    }
#pragma unroll
    for (int mi=0;mi<2;++mi)
#pragma unroll
      for (int n=0;n<8;++n)
#pragma unroll
        for (int j=0;j<4;++j) {
          int r = w*32 + mi*16 + l4*4 + j, c = n*16 + l15;
          S0[r*128 + c] = -g0[mi][n][j];
        }
  }
}

// ---------------- double linear-recurrence scan over chunks (in place) ----------------

__global__ __launch_bounds__(256) void scan_kernel(
    float* __restrict__ S, const float* __restrict__ mg, const float* __restrict__ d1m)
{
  int bidx = blockIdx.x;              // (m*16+bh)*64 + eblk
  int eblk = bidx & 63;
  int mbh = bidx >> 6;                // 0..31
  int bh = mbh & 15;
  int e = eblk*256 + threadIdx.x;
  float* base = S + (size_t)mbh*64*16384 + e;
  const float* g1 = mg + bh*64;
  const float* g2 = d1m + bh*64;
  float mom = 0.f, upd = 0.f;
  for (int c2=0; c2<64; ++c2) {
    float s = base[(size_t)c2*16384];
    mom = g1[c2]*mom + s;            // momentum scan
    upd = g2[c2]*upd + mom;          // update scan
    base[(size_t)c2*16384] = upd;
  }
}

// ---------------- per-chunk retrieval ----------------

__global__ __launch_bounds__(256) void retrieve_kernel(
    const u16* __restrict__ qn, const float* __restrict__ U,
    const float* __restrict__ w0f, const float* __restrict__ w1f,
    const float* __restrict__ gamma, const float* __restrict__ gate,
    u16* __restrict__ vals)
{
  __shared__ __align__(16) u16 W0s[128*128];  // (w0+u0)^T, [n][k]
  __shared__ __align__(16) u16 W1s[128*128];
  __shared__ __align__(16) u16 QA[64*128];    // Q tile, later reused for silu(x)
  int bid = blockIdx.x; int bh = bid>>6, ch = bid&63;
  int b = bh>>3, h = bh&7;
  int tid = threadIdx.x;
  int w = tid>>6, lane = tid&63;
  int l15 = lane&15, l4 = lane>>4;
  const float* U0 = U + ((size_t)bh*64 + ch)*16384;
  const float* U1 = U + ((size_t)(16+bh)*64 + ch)*16384;
  for (int it=0; it<64; ++it) {
    int e = it*256 + tid;
    int k = e>>7, n = e&127;
    W0s[sidx(n,k)] = f2b(w0f[e] + U0[e]);
    W1s[sidx(n,k)] = f2b(w1f[e] + U1[e]);
  }
#pragma unroll
  for (int it=0; it<4; ++it) {
    int gi = it*256 + tid; int row = gi>>4, g = gi&15;
    int posn = ch*64 + row + 63;       // natural position of shifted query row
    short8 v;
    if (posn < 4096) v = *(const short8*)&qn[((size_t)(b*4096+posn))*1024 + h*128 + g*8];
    else {
#pragma unroll
      for (int i=0;i<8;++i) v[i]=0;
    }
    *(short8*)&QA[row*128 + ((g ^ (row&7))<<3)] = v;
  }
  __syncthreads();
  // x = q @ (w0+u0)
  f32x4 xx[8] = {};
#pragma unroll
  for (int ks=0; ks<4; ++ks) {
    short8 af = frag_row_lds128(QA, w*16 + l15, ks, l4);
#pragma unroll
    for (int n=0;n<8;++n) {
      short8 bf = frag_row_lds128(W0s, n*16 + l15, ks, l4);
      xx[n] = __builtin_amdgcn_mfma_f32_16x16x32_bf16(af, bf, xx[n], 0,0,0);
    }
  }
  // silu(x) overwrites own rows of QA (same-wave rows only -> no barrier needed)
#pragma unroll
  for (int n=0;n<8;++n)
#pragma unroll
    for (int j=0;j<4;++j) {
      int r = w*16 + l4*4 + j, c = n*16 + l15;
      float xv = xx[n][j];
      QA[sidx(r,c)] = f2b(xv * sigm(xv));
    }
  // vals = silu(x) @ (w1+u1)
  f32x4 vv[8] = {};
#pragma unroll
  for (int ks=0; ks<4; ++ks) {
    short8 af = frag_row_lds128(QA, w*16 + l15, ks, l4);
#pragma unroll
    for (int n=0;n<8;++n) {
      short8 bf = frag_row_lds128(W1s, n*16 + l15, ks, l4);
      vv[n] = __builtin_amdgcn_mfma_f32_16x16x32_bf16(af, bf, vv[n], 0,0,0);
    }
  }
  // epilogue: rmsnorm over dh, *(1+gamma), *gate, store at natural pos
#pragma unroll
  for (int j=0;j<4;++j) {
    float ssq = 0.f;
#pragma unroll
    for (int n=0;n<8;++n) ssq += vv[n][j]*vv[n][j];
    ssq += __shfl_xor(ssq,1); ssq += __shfl_xor(ssq,2);
    ssq += __shfl_xor(ssq,4); ssq += __shfl_xor(ssq,8);
    float rms = rsqrtf(ssq*(1.f/128.f) + 1e-6f);
    int r = w*16 + l4*4 + j;
    int posn = ch*64 + r + 63;
    if (posn < 4096) {
      float gt = gate[(size_t)bh*4096 + posn];
      size_t orow = ((size_t)(b*4096+posn))*1024 + h*128;
#pragma unroll
      for (int n=0;n<8;++n) {
        int c = n*16 + l15;
        vals[orow + c] = f2b(vv[n][j]*rms*(1.f + gamma[h*128+c])*gt);
      }
    }
  }
}

extern "C" void kernel_launch(void* const* d_in, const int* in_sizes, int n_in,
                              void* d_out, int out_size, void* d_ws, size_t ws_size,
                              hipStream_t stream) {
  const float* seq    = (const float*)d_in[0];
  const float* gstore = (const float*)d_in[1];
  const float* gret   = (const float*)d_in[2];
  const float* wkv    = (const float*)d_in[3];
  const float* wq     = (const float*)d_in[4];
  const float* wstep  = (const float*)d_in[5];
  const float* wmom   = (const float*)d_in[6];
  const float* wdec   = (const float*)d_in[7];
  const float* wgate  = (const float*)d_in[8];
  const float* wcomb  = (const float*)d_in[9];
  const float* gamma  = (const float*)d_in[10];
  const float* w0f    = (const float*)d_in[11];
  const float* w1f    = (const float*)d_in[12];
  float* out = (float*)d_out;
  (void)in_sizes; (void)n_in; (void)out_size; (void)ws_size;

  char* p = (char*)d_ws;
  size_t off = 0;
  auto alloc = [&](size_t bytes) -> void* {
    void* r = p + off; off += (bytes + 255) & ~(size_t)255; return r;
  };
  u16* wkvT   = (u16*)alloc((size_t)2048*1024*2);
  u16* wqT    = (u16*)alloc((size_t)1024*1024*2);
  u16* wcombT = (u16*)alloc((size_t)1024*1024*2);
  u16* w0b    = (u16*)alloc(16384*2);
  u16* w0T    = (u16*)alloc(16384*2);
  u16* w1b    = (u16*)alloc(16384*2);
  u16* w1T    = (u16*)alloc(16384*2);
  u16* ss     = (u16*)alloc((size_t)NTOK*1024*2);
  u16* sr     = (u16*)alloc((size_t)NTOK*1024*2);
  u16* kvout  = (u16*)alloc((size_t)NTOK*2048*2);
  u16* qn     = (u16*)alloc((size_t)NTOK*1024*2);
  u16* vals   = (u16*)alloc((size_t)NTOK*1024*2);
  float* lr   = (float*)alloc((size_t)16*4096*4);
  float* gate = (float*)alloc((size_t)16*4096*4);
  float* mg   = (float*)alloc(1024*4);
  float* d1m  = (float*)alloc(1024*4);
  float* S    = (float*)alloc((size_t)32*64*16384*4);
  (void)w0b;

  transpose_bf16<<<dim3(512),dim3(256),0,stream>>>(wkv, wkvT, 1024, 2048);
  transpose_bf16<<<dim3(256),dim3(256),0,stream>>>(wq, wqT, 1024, 1024);
  transpose_bf16<<<dim3(256),dim3(256),0,stream>>>(wcomb, wcombT, 1024, 1024);
  smallprep<<<dim3(64),dim3(256),0,stream>>>(w0f, w1f, w0b, w0T, w1b, w1T);
  norms_kernel<<<dim3(NTOK),dim3(256),0,stream>>>(seq, gstore, gret, wstep, wgate, ss, sr, lr, gate);
  chunkgates_kernel<<<dim3(128),dim3(256),0,stream>>>(ss, wmom, wdec, mg, d1m);
  gemm_bt<<<dim3(16,64),dim3(256),0,stream>>>(ss, wkvT, kvout, 8192, 2048, 1024, 0);
  gemm_bt<<<dim3(8,64),dim3(256),0,stream>>>(sr, wqT, qn, 8192, 1024, 1024, 0);
  grad_kernel<<<dim3(1024),dim3(256),0,stream>>>(kvout, lr, w0T, w1T, w1b, S);
  scan_kernel<<<dim3(2048),dim3(256),0,stream>>>(S, mg, d1m);
  hipMemsetAsync(vals, 0, (size_t)NTOK*1024*2, stream);
  retrieve_kernel<<<dim3(1024),dim3(256),0,stream>>>(qn, S, w0f, w1f, gamma, gate, vals);
  gemm_bt<<<dim3(8,64),dim3(256),0,stream>>>(vals, wcombT, out, 8192, 1024, 1024, 1);
}

// Round 2
// 367.972 us; speedup vs baseline: 1.0195x; 1.0195x over previous
//
#include <hip/hip_runtime.h>
#include <stdint.h>

// NeuralMemory (Titans-style) for MI355X / gfx950.
//  norms -> kv/q GEMMs -> per-chunk MLP grads (transposed bf16 S) ->
//  double linear scan (bf16, f32 state) -> retrieval (register W=w+U) ->
//  combine GEMM. Shift-by-63 handled via natural indexing.

#define SEQ 4096
#define NTOK 8192

typedef unsigned short u16;
typedef __attribute__((ext_vector_type(8))) short short8;
typedef __attribute__((ext_vector_type(4))) short short4v;
typedef __attribute__((ext_vector_type(4))) float f32x4;

__device__ __forceinline__ u16 f2b(float f) {
  union { float f; uint32_t u; } c; c.f = f;
  uint32_t u = c.u;
  uint32_t r = (u + 0x7fffu + ((u >> 16) & 1u)) >> 16;
  return (u16)r;
}
__device__ __forceinline__ float b2f(u16 h) {
  union { uint32_t u; float f; } c; c.u = ((uint32_t)h) << 16;
  return c.f;
}
__device__ __forceinline__ float sigm(float x) { return 1.f / (1.f + __expf(-x)); }

// XOR-swizzled element index inside a [rows][128] bf16 LDS tile (16B-granule swizzle)
__device__ __forceinline__ int sidx(int r, int c) {
  return r*128 + ((((c>>3) ^ (r&7))<<3) | (c&7));
}
// contiguous 8-bf16 fragment from row-major [.][128] tile
__device__ __forceinline__ short8 frag_row_lds128(const u16* buf, int row, int ks, int l4) {
  int g = ks*4 + l4;
  return *(const short8*)&buf[row*128 + ((g ^ (row&7))<<3)];
}
// ---- transposed [128][64] tiles, dual-XOR swizzle (write- and read-conflict-free) ----
__device__ __forceinline__ int swzT(int n, int k) {
  return n*64 + ((((k>>3) ^ (n&7) ^ ((n>>3)&7)) & 7)<<3) + (k&7);
}
__device__ __forceinline__ short8 frag_T(const u16* buf, int n, int ks, int l4) {
  int gk = ks*4 + l4;
  int off = (gk ^ (n&7) ^ ((n>>3)&7)) & 7;
  return *(const short8*)&buf[n*64 + off*8];
}
// packed write of 4 consecutive-k values (k0 aligned to 4) into T tile
__device__ __forceinline__ void t_write4(u16* buf, int n, int k0,
                                         float v0, float v1, float v2, float v3) {
  int addr = n*64 + ((((k0>>3) ^ (n&7) ^ ((n>>3)&7)) & 7)<<3) + (k0&7);
  short4v p; p[0]=(short)f2b(v0); p[1]=(short)f2b(v1); p[2]=(short)f2b(v2); p[3]=(short)f2b(v3);
  *(short4v*)&buf[addr] = p;
}

// ---------------- weight prep ----------------

__global__ __launch_bounds__(256) void transpose_bf16(
    const float* __restrict__ src, u16* __restrict__ dst, int R, int C)
{
  __shared__ u16 tile[64*66];
  int tiles_x = C >> 6;
  int tx = blockIdx.x % tiles_x, ty = blockIdx.x / tiles_x;
  int c0 = tx*64, r0 = ty*64;
#pragma unroll
  for (int it=0; it<16; ++it) {
    int idx = it*256 + threadIdx.x;
    int rr = idx>>6, cc = idx&63;
    tile[cc*66 + rr] = f2b(src[(size_t)(r0+rr)*C + c0+cc]);
  }
  __syncthreads();
#pragma unroll
  for (int it=0; it<16; ++it) {
    int idx = it*256 + threadIdx.x;
    int rr = idx>>6, cc = idx&63;
    dst[(size_t)(c0+rr)*R + r0+cc] = tile[rr*66 + cc];
  }
}

__global__ __launch_bounds__(256) void smallprep(
    const float* __restrict__ w0, const float* __restrict__ w1,
    u16* __restrict__ w0T, u16* __restrict__ w1b, u16* __restrict__ w1T)
{
  int id = blockIdx.x*256 + threadIdx.x;   // 0..16383
  int i = id>>7, j = id&127;
  float a = w0[id], b = w1[id];
  w1b[id] = f2b(b);
  w0T[j*128+i] = f2b(a); w1T[j*128+i] = f2b(b);
}

// ---------------- norms + per-token gates ----------------

__global__ __launch_bounds__(256) void norms_kernel(
    const float* __restrict__ seq, const float* __restrict__ gs,
    const float* __restrict__ gr, const float* __restrict__ wstep,
    const float* __restrict__ wgate, u16* __restrict__ ss,
    u16* __restrict__ sr, float* __restrict__ lr, float* __restrict__ gate)
{
  int t = blockIdx.x; int b = t>>12, pos = t&4095;
  int tid = threadIdx.x;
  const float* row = seq + (size_t)t*1024;
  float x[4]; float ssq = 0.f;
#pragma unroll
  for (int i=0;i<4;++i){ x[i]=row[i*256+tid]; ssq += x[i]*x[i]; }
  for (int m=32;m;m>>=1) ssq += __shfl_xor(ssq, m);
  __shared__ float red[4];
  __shared__ float r2[4][16];
  int wv = tid>>6;
  if ((tid&63)==0) red[wv] = ssq;
  __syncthreads();
  float tot = red[0]+red[1]+red[2]+red[3];
  float inv = rsqrtf(tot*(1.f/1024.f) + 1e-6f);
  float ps[8], pg[8];
#pragma unroll
  for (int h=0;h<8;++h){ ps[h]=0.f; pg[h]=0.f; }
#pragma unroll
  for (int i=0;i<4;++i) {
    int d = i*256+tid;
    float sv = x[i]*inv*gs[d];
    float rv = x[i]*inv*gr[d];
    ss[(size_t)t*1024+d] = f2b(sv);
    sr[(size_t)t*1024+d] = f2b(rv);
#pragma unroll
    for (int h=0;h<8;++h) { ps[h] += sv*wstep[d*8+h]; pg[h] += rv*wgate[d*8+h]; }
  }
#pragma unroll
  for (int h=0;h<8;++h)
    for (int m=32;m;m>>=1){ ps[h] += __shfl_xor(ps[h],m); pg[h] += __shfl_xor(pg[h],m); }
  if ((tid&63)==0) {
#pragma unroll
    for (int h=0;h<8;++h){ r2[wv][h]=ps[h]; r2[wv][8+h]=pg[h]; }
  }
  __syncthreads();
  if (tid < 16) {
    float s = r2[0][tid]+r2[1][tid]+r2[2][tid]+r2[3][tid];
    float sg = sigm(s);
    if (tid<8) lr[((size_t)(b*8+tid))*4096 + pos] = sg*0.01f;
    else gate[((size_t)(b*8+(tid-8)))*4096 + pos] = sg;
  }
}

// ---------------- per-chunk gates from cmean ----------------

__global__ __launch_bounds__(256) void chunkgates_kernel(
    const u16* __restrict__ ss, const float* __restrict__ wmom,
    const float* __restrict__ wdec, float* __restrict__ mg,
    float* __restrict__ d1m)
{
  int bc = blockIdx.x; int b = bc>>6, ch = bc&63;
  size_t t0 = (size_t)(b*4096 + ch*64)*1024;
  int tid = threadIdx.x;
  float cm[4]; cm[0]=cm[1]=cm[2]=cm[3]=0.f;
  for (int tok=0; tok<64; ++tok) {
#pragma unroll
    for (int i=0;i<4;++i)
      cm[i] += b2f(ss[t0 + (size_t)tok*1024 + i*256 + tid]);
  }
  float pm[8], pd[8];
#pragma unroll
  for (int h=0;h<8;++h){ pm[h]=0.f; pd[h]=0.f; }
#pragma unroll
  for (int i=0;i<4;++i) {
    float v = cm[i]*(1.f/64.f);
    int d = i*256+tid;
#pragma unroll
    for (int h=0;h<8;++h){ pm[h]+=v*wmom[d*8+h]; pd[h]+=v*wdec[d*8+h]; }
  }
#pragma unroll
  for (int h=0;h<8;++h)
    for (int m=32;m;m>>=1){ pm[h] += __shfl_xor(pm[h],m); pd[h] += __shfl_xor(pd[h],m); }
  __shared__ float r2[4][16];
  int wv = tid>>6;
  if ((tid&63)==0) {
#pragma unroll
    for (int h=0;h<8;++h){ r2[wv][h]=pm[h]; r2[wv][8+h]=pd[h]; }
  }
  __syncthreads();
  if (tid < 16) {
    float s = r2[0][tid]+r2[1][tid]+r2[2][tid]+r2[3][tid];
    if (tid<8) mg[(b*8+tid)*64 + ch] = sigm(s);
    else d1m[(b*8+(tid-8))*64 + ch] = 1.f - sigm(s);
  }
}

// ---------------- generic bf16 GEMM: C = A(MxK) @ Bt(NxK)^T ----------------

__global__ __launch_bounds__(256) void gemm_bt(
    const u16* __restrict__ A, const u16* __restrict__ Bt,
    void* __restrict__ C, int M, int N, int K, int out_f32)
{
  __shared__ __align__(16) u16 As[128*64];
  __shared__ __align__(16) u16 Bs[128*64];
  int tid = threadIdx.x;
  int wv = tid>>6, lane = tid&63;
  int wr = wv>>1, wc = wv&1;
  int l15 = lane&15, l4 = lane>>4;
  // XCD-aware bijective block swizzle (grid sizes here are all %8==0)
  int nwg = gridDim.x*gridDim.y;
  int wg  = blockIdx.y*gridDim.x + blockIdx.x;
  int cpx = nwg >> 3;
  int swz = (wg & 7)*cpx + (wg >> 3);
  int bx = swz % gridDim.x, by = swz / gridDim.x;
  int brow = by*128, bcol = bx*128;
  f32x4 acc[4][4] = {};
  for (int kt=0; kt<K; kt+=64) {
#pragma unroll
    for (int it=0; it<4; ++it) {
      int gi = it*256 + tid;
      int row = gi>>3, g = gi&7;
      int sg = g ^ (row&7);
      *(short8*)&As[row*64 + sg*8] = *(const short8*)&A[(size_t)(brow+row)*K + kt + g*8];
      *(short8*)&Bs[row*64 + sg*8] = *(const short8*)&Bt[(size_t)(bcol+row)*K + kt + g*8];
    }
    __syncthreads();
#pragma unroll
    for (int ks=0; ks<2; ++ks) {
      short8 af[4], bfr[4];
#pragma unroll
      for (int m=0;m<4;++m) {
        int row = wr*64 + m*16 + l15;
        int g = ks*4 + l4;
        af[m] = *(const short8*)&As[row*64 + ((g ^ (row&7))<<3)];
      }
#pragma unroll
      for (int n=0;n<4;++n) {
        int row = wc*64 + n*16 + l15;
        int g = ks*4 + l4;
        bfr[n] = *(const short8*)&Bs[row*64 + ((g ^ (row&7))<<3)];
      }
#pragma unroll
      for (int m=0;m<4;++m)
#pragma unroll
        for (int n=0;n<4;++n)
          acc[m][n] = __builtin_amdgcn_mfma_f32_16x16x32_bf16(af[m], bfr[n], acc[m][n], 0,0,0);
    }
    __syncthreads();
  }
#pragma unroll
  for (int m=0;m<4;++m) {
#pragma unroll
    for (int n=0;n<4;++n) {
      int col = bcol + wc*64 + n*16 + l15;
#pragma unroll
      for (int j=0;j<4;++j) {
        int row = brow + wr*64 + m*16 + l4*4 + j;
        if (out_f32) ((float*)C)[(size_t)row*N + col] = acc[m][n][j];
        else ((u16*)C)[(size_t)row*N + col] = f2b(acc[m][n][j]);
      }
    }
  }
}

// ---------------- per-chunk MLP gradients -> transposed bf16 surprise ----------------
// loss = sum_r lr[r] * mean_e (pred[r,e]-v[r,e])^2 ; pred = silu(k@w0)@w1
// S0T[e_mid][e_in]  = -(k^T @ dx1)^T  = -(dx1^T @ k)
// S1T[e_out][e_mid] = -(a^T @ dpred)^T = -(dpred^T @ a)

__global__ __launch_bounds__(256) void grad_kernel(
    const u16* __restrict__ kvout, const float* __restrict__ lr,
    const u16* __restrict__ w0T, const u16* __restrict__ w1T,
    const u16* __restrict__ w1b, u16* __restrict__ S)
{
  // bufA: Kt-row -> Al-row -> DlT ; bufB: KtT ; bufC: AlT ; bufD: Vt-row -> Dl-row -> DXT
  __shared__ __align__(16) u16 bufA[64*128];
  __shared__ __align__(16) u16 bufB[128*64];
  __shared__ __align__(16) u16 bufC[128*64];
  __shared__ __align__(16) u16 bufD[64*128];
  __shared__ float lr_s[64];
  int bid = blockIdx.x;
  int bh = bid>>6, ch = bid&63;
  int b = bh>>3, h = bh&7;
  int tid = threadIdx.x;
  int w = tid>>6, lane = tid&63;
  int l15 = lane&15, l4 = lane>>4;
  size_t t0 = (size_t)(b*4096 + ch*64);

  // stage: Kt-row(bufA) + KtT(bufB) + Vt-row(bufD)
#pragma unroll
  for (int it=0; it<4; ++it) {
    int gi = it*256 + tid;
    int row = gi>>4, g = gi&15;
    short8 kv8 = *(const short8*)&kvout[(t0+row)*2048 + h*128 + g*8];
    short8 vv8 = *(const short8*)&kvout[(t0+row)*2048 + 1024 + h*128 + g*8];
    int sg = g ^ (row&7);
    *(short8*)&bufA[row*128 + sg*8] = kv8;
    *(short8*)&bufD[row*128 + sg*8] = vv8;
#pragma unroll
    for (int i=0;i<8;++i) bufB[swzT(g*8+i, row)] = (u16)(short)kv8[i];
  }
  if (tid < 64) lr_s[tid] = lr[(size_t)bh*4096 + ch*64 + tid];
  __syncthreads();   // B1

  // x1 = k @ w0 (wave w owns rows w*16..+15)
  f32x4 x1[8] = {};
#pragma unroll
  for (int ks=0; ks<4; ++ks) {
    short8 af = frag_row_lds128(bufA, w*16 + l15, ks, l4);
    int kof = ks*32 + l4*8;
#pragma unroll
    for (int n=0;n<8;++n) {
      short8 bf = *(const short8*)&w0T[(size_t)(n*16+l15)*128 + kof];
      x1[n] = __builtin_amdgcn_mfma_f32_16x16x32_bf16(af, bf, x1[n], 0,0,0);
    }
  }
  // a = silu(x1): Al-row into bufA (own rows, overwrites own Kt rows) + AlT into bufC
  int r0 = w*16 + l4*4;
#pragma unroll
  for (int n=0;n<8;++n) {
    int c = n*16 + l15;
    float a0 = x1[n][0]*sigm(x1[n][0]);
    float a1 = x1[n][1]*sigm(x1[n][1]);
    float a2 = x1[n][2]*sigm(x1[n][2]);
    float a3 = x1[n][3]*sigm(x1[n][3]);
    bufA[sidx(r0+0,c)] = f2b(a0);
    bufA[sidx(r0+1,c)] = f2b(a1);
    bufA[sidx(r0+2,c)] = f2b(a2);
    bufA[sidx(r0+3,c)] = f2b(a3);
    t_write4(bufC, c, r0, a0, a1, a2, a3);
  }
  // pred = a @ w1 (reads own Al rows)
  f32x4 pr[8] = {};
#pragma unroll
  for (int ks=0; ks<4; ++ks) {
    short8 af = frag_row_lds128(bufA, w*16 + l15, ks, l4);
    int kof = ks*32 + l4*8;
#pragma unroll
    for (int n=0;n<8;++n) {
      short8 bf = *(const short8*)&w1T[(size_t)(n*16+l15)*128 + kof];
      pr[n] = __builtin_amdgcn_mfma_f32_16x16x32_bf16(af, bf, pr[n], 0,0,0);
    }
  }
  // dpred = (2/128)*lr*(pred - v) : read Vt (own rows) pre-barrier
  float dpv[8][4];
#pragma unroll
  for (int n=0;n<8;++n) {
    int c = n*16 + l15;
#pragma unroll
    for (int j=0;j<4;++j)
      dpv[n][j] = 0.015625f * lr_s[r0+j] * (pr[n][j] - b2f(bufD[sidx(r0+j,c)]));
  }
  __syncthreads();   // B3: all Al-row reads + Vt reads done
  // write Dl-row (bufD, own rows) + DlT (bufA)
#pragma unroll
  for (int n=0;n<8;++n) {
    int c = n*16 + l15;
    bufD[sidx(r0+0,c)] = f2b(dpv[n][0]);
    bufD[sidx(r0+1,c)] = f2b(dpv[n][1]);
    bufD[sidx(r0+2,c)] = f2b(dpv[n][2]);
    bufD[sidx(r0+3,c)] = f2b(dpv[n][3]);
    t_write4(bufA, c, r0, dpv[n][0], dpv[n][1], dpv[n][2], dpv[n][3]);
  }
  // da = dpred @ w1^T (reads own Dl rows)
  f32x4 da[8] = {};
#pragma unroll
  for (int ks=0; ks<4; ++ks) {
    short8 af = frag_row_lds128(bufD, w*16 + l15, ks, l4);
    int kof = ks*32 + l4*8;
#pragma unroll
    for (int n=0;n<8;++n) {
      short8 bf = *(const short8*)&w1b[(size_t)(n*16+l15)*128 + kof];
      da[n] = __builtin_amdgcn_mfma_f32_16x16x32_bf16(af, bf, da[n], 0,0,0);
    }
  }
  __syncthreads();   // B4: all da reads of Dl-row done
  // dx1 = da * silu'(x1) -> DXT (bufD)
#pragma unroll
  for (int n=0;n<8;++n) {
    int c = n*16 + l15;
    float dx[4];
#pragma unroll
    for (int j=0;j<4;++j) {
      float xv = x1[n][j];
      float sg = sigm(xv);
      dx[j] = da[n][j]*(sg*(1.f + xv*(1.f - sg)));
    }
    t_write4(bufD, c, r0, dx[0], dx[1], dx[2], dx[3]);
  }
  __syncthreads();   // B5: all T tiles ready

  u16* S0 = S + ((size_t)bh*64 + ch)*16384;
  u16* S1 = S + ((size_t)(16+bh)*64 + ch)*16384;
  // gw1T = dpred^T @ a : A=DlT(bufA), B=AlT(bufC). wave w owns out rows w*32..+31.
  {
    f32x4 g1[2][8] = {};
#pragma unroll
    for (int ks=0; ks<2; ++ks) {
      short8 af[2];
#pragma unroll
      for (int mi=0; mi<2; ++mi)
        af[mi] = frag_T(bufA, w*32 + mi*16 + l15, ks, l4);
#pragma unroll
      for (int n=0;n<8;++n) {
        short8 bf = frag_T(bufC, n*16 + l15, ks, l4);
#pragma unroll
        for (int mi=0;mi<2;++mi)
          g1[mi][n] = __builtin_amdgcn_mfma_f32_16x16x32_bf16(af[mi], bf, g1[mi][n], 0,0,0);
      }
    }
#pragma unroll
    for (int mi=0;mi<2;++mi)
#pragma unroll
      for (int n=0;n<8;++n)
#pragma unroll
        for (int j=0;j<4;++j) {
          int m = w*32 + mi*16 + l4*4 + j, c = n*16 + l15;
          S1[m*128 + c] = f2b(-g1[mi][n][j]);
        }
  }
  // gw0T = dx1^T @ k : A=DXT(bufD), B=KtT(bufB)
  {
    f32x4 g0[2][8] = {};
#pragma unroll
    for (int ks=0; ks<2; ++ks) {
      short8 af[2];
#pragma unroll
      for (int mi=0; mi<2; ++mi)
        af[mi] = frag_T(bufD, w*32 + mi*16 + l15, ks, l4);
#pragma unroll
      for (int n=0;n<8;++n) {
        short8 bf = frag_T(bufB, n*16 + l15, ks, l4);
#pragma unroll
        for (int mi=0;mi<2;++mi)
          g0[mi][n] = __builtin_amdgcn_mfma_f32_16x16x32_bf16(af[mi], bf, g0[mi][n], 0,0,0);
      }
    }
#pragma unroll
    for (int mi=0;mi<2;++mi)
#pragma unroll
      for (int n=0;n<8;++n)
#pragma unroll
        for (int j=0;j<4;++j) {
          int m = w*32 + mi*16 + l4*4 + j, c = n*16 + l15;
          S0[m*128 + c] = f2b(-g0[mi][n][j]);
        }
  }
}

// ---------------- double linear-recurrence scan over chunks (in place, bf16) ----------------

__global__ __launch_bounds__(256) void scan_kernel(
    u16* __restrict__ S, const float* __restrict__ mg, const float* __restrict__ d1m)
{
  int bidx = blockIdx.x;              // (m*16+bh)*64 + eblk
  int eblk = bidx & 63;
  int mbh = bidx >> 6;                // 0..31
  int bh = mbh & 15;
  int e = eblk*256 + threadIdx.x;
  u16* base = S + (size_t)mbh*64*16384 + e;
  const float* g1 = mg + bh*64;
  const float* g2 = d1m + bh*64;
  float mom = 0.f, upd = 0.f;
  for (int c2=0; c2<64; ++c2) {
    float s = b2f(base[(size_t)c2*16384]);
    mom = g1[c2]*mom + s;            // momentum scan
    upd = g2[c2]*upd + mom;          // update scan
    base[(size_t)c2*16384] = f2b(upd);
  }
}

// ---------------- per-chunk retrieval (W = w + U summed in registers) ----------------

__global__ __launch_bounds__(256) void retrieve_kernel(
    const u16* __restrict__ qn, const u16* __restrict__ U,
    const u16* __restrict__ w0T, const u16* __restrict__ w1T,
    const float* __restrict__ gamma, const float* __restrict__ gate,
    u16* __restrict__ vals)
{
  __shared__ __align__(16) u16 QA[64*128];    // Q tile, later reused for silu(x)
  int bid = blockIdx.x; int bh = bid>>6, ch = bid&63;
  int b = bh>>3, h = bh&7;
  int tid = threadIdx.x;
  int w = tid>>6, lane = tid&63;
  int l15 = lane&15, l4 = lane>>4;
  const u16* U0 = U + ((size_t)bh*64 + ch)*16384;
  const u16* U1 = U + ((size_t)(16+bh)*64 + ch)*16384;
#pragma unroll
  for (int it=0; it<4; ++it) {
    int gi = it*256 + tid; int row = gi>>4, g = gi&15;
    int posn = ch*64 + row + 63;       // natural position of shifted query row
    short8 v;
    if (posn < 4096) v = *(const short8*)&qn[((size_t)(b*4096+posn))*1024 + h*128 + g*8];
    else {
#pragma unroll
      for (int i=0;i<8;++i) v[i]=0;
    }
    *(short8*)&QA[row*128 + ((g ^ (row&7))<<3)] = v;
  }
  __syncthreads();
  // x = q @ (w0+u0): B-fragments built in registers from bf16 w0T + U0T
  f32x4 xx[8] = {};
#pragma unroll
  for (int ks=0; ks<4; ++ks) {
    short8 af = frag_row_lds128(QA, w*16 + l15, ks, l4);
    int kof = ks*32 + l4*8;
#pragma unroll
    for (int n=0;n<8;++n) {
      size_t o = (size_t)(n*16+l15)*128 + kof;
      short8 wa = *(const short8*)&w0T[o];
      short8 ua = *(const short8*)&U0[o];
      short8 bf;
#pragma unroll
      for (int i=0;i<8;++i) bf[i] = (short)f2b(b2f((u16)(short)wa[i]) + b2f((u16)(short)ua[i]));
      xx[n] = __builtin_amdgcn_mfma_f32_16x16x32_bf16(af, bf, xx[n], 0,0,0);
    }
  }
  // silu(x) overwrites own rows of QA
  int r0 = w*16 + l4*4;
#pragma unroll
  for (int n=0;n<8;++n) {
    int c = n*16 + l15;
#pragma unroll
    for (int j=0;j<4;++j) {
      float xv = xx[n][j];
      QA[sidx(r0+j,c)] = f2b(xv * sigm(xv));
    }
  }
  // vals = silu(x) @ (w1+u1)
  f32x4 vv[8] = {};
#pragma unroll
  for (int ks=0; ks<4; ++ks) {
    short8 af = frag_row_lds128(QA, w*16 + l15, ks, l4);
    int kof = ks*32 + l4*8;
#pragma unroll
    for (int n=0;n<8;++n) {
      size_t o = (size_t)(n*16+l15)*128 + kof;
      short8 wa = *(const short8*)&w1T[o];
      short8 ua = *(const short8*)&U1[o];
      short8 bf;
#pragma unroll
      for (int i=0;i<8;++i) bf[i] = (short)f2b(b2f((u16)(short)wa[i]) + b2f((u16)(short)ua[i]));
      vv[n] = __builtin_amdgcn_mfma_f32_16x16x32_bf16(af, bf, vv[n], 0,0,0);
    }
  }
  // epilogue: rmsnorm over dh, *(1+gamma), *gate, store at natural pos
#pragma unroll
  for (int j=0;j<4;++j) {
    float ssq = 0.f;
#pragma unroll
    for (int n=0;n<8;++n) ssq += vv[n][j]*vv[n][j];
    ssq += __shfl_xor(ssq,1); ssq += __shfl_xor(ssq,2);
    ssq += __shfl_xor(ssq,4); ssq += __shfl_xor(ssq,8);
    float rms = rsqrtf(ssq*(1.f/128.f) + 1e-6f);
    int r = r0 + j;
    int posn = ch*64 + r + 63;
    if (posn < 4096) {
      float gt = gate[(size_t)bh*4096 + posn];
      size_t orow = ((size_t)(b*4096+posn))*1024 + h*128;
#pragma unroll
      for (int n=0;n<8;++n) {
        int c = n*16 + l15;
        vals[orow + c] = f2b(vv[n][j]*rms*(1.f + gamma[h*128+c])*gt);
      }
    }
  }
}

extern "C" void kernel_launch(void* const* d_in, const int* in_sizes, int n_in,
                              void* d_out, int out_size, void* d_ws, size_t ws_size,
                              hipStream_t stream) {
  const float* seq    = (const float*)d_in[0];
  const float* gstore = (const float*)d_in[1];
  const float* gret   = (const float*)d_in[2];
  const float* wkv    = (const float*)d_in[3];
  const float* wq     = (const float*)d_in[4];
  const float* wstep  = (const float*)d_in[5];
  const float* wmom   = (const float*)d_in[6];
  const float* wdec   = (const float*)d_in[7];
  const float* wgate  = (const float*)d_in[8];
  const float* wcomb  = (const float*)d_in[9];
  const float* gamma  = (const float*)d_in[10];
  const float* w0f    = (const float*)d_in[11];
  const float* w1f    = (const float*)d_in[12];
  float* out = (float*)d_out;
  (void)in_sizes; (void)n_in; (void)out_size; (void)ws_size;

  char* p = (char*)d_ws;
  size_t off = 0;
  auto alloc = [&](size_t bytes) -> void* {
    void* r = p + off; off += (bytes + 255) & ~(size_t)255; return r;
  };
  u16* wkvT   = (u16*)alloc((size_t)2048*1024*2);
  u16* wqT    = (u16*)alloc((size_t)1024*1024*2);
  u16* wcombT = (u16*)alloc((size_t)1024*1024*2);
  u16* w0T    = (u16*)alloc(16384*2);
  u16* w1b    = (u16*)alloc(16384*2);
  u16* w1T    = (u16*)alloc(16384*2);
  u16* ss     = (u16*)alloc((size_t)NTOK*1024*2);
  u16* sr     = (u16*)alloc((size_t)NTOK*1024*2);
  u16* kvout  = (u16*)alloc((size_t)NTOK*2048*2);
  u16* qn     = (u16*)alloc((size_t)NTOK*1024*2);
  u16* vals   = (u16*)alloc((size_t)NTOK*1024*2);
  float* lr   = (float*)alloc((size_t)16*4096*4);
  float* gate = (float*)alloc((size_t)16*4096*4);
  float* mg   = (float*)alloc(1024*4);
  float* d1m  = (float*)alloc(1024*4);
  u16* S      = (u16*)alloc((size_t)32*64*16384*2);

  transpose_bf16<<<dim3(512),dim3(256),0,stream>>>(wkv, wkvT, 1024, 2048);
  transpose_bf16<<<dim3(256),dim3(256),0,stream>>>(wq, wqT, 1024, 1024);
  transpose_bf16<<<dim3(256),dim3(256),0,stream>>>(wcomb, wcombT, 1024, 1024);
  smallprep<<<dim3(64),dim3(256),0,stream>>>(w0f, w1f, w0T, w1b, w1T);
  norms_kernel<<<dim3(NTOK),dim3(256),0,stream>>>(seq, gstore, gret, wstep, wgate, ss, sr, lr, gate);
  chunkgates_kernel<<<dim3(128),dim3(256),0,stream>>>(ss, wmom, wdec, mg, d1m);
  gemm_bt<<<dim3(16,64),dim3(256),0,stream>>>(ss, wkvT, kvout, 8192, 2048, 1024, 0);
  gemm_bt<<<dim3(8,64),dim3(256),0,stream>>>(sr, wqT, qn, 8192, 1024, 1024, 0);
  grad_kernel<<<dim3(1024),dim3(256),0,stream>>>(kvout, lr, w0T, w1T, w1b, S);
  scan_kernel<<<dim3(2048),dim3(256),0,stream>>>(S, mg, d1m);
  hipMemsetAsync(vals, 0, (size_t)NTOK*1024*2, stream);
  retrieve_kernel<<<dim3(1024),dim3(256),0,stream>>>(qn, S, w0T, w1T, gamma, gate, vals);
  gemm_bt<<<dim3(8,64),dim3(256),0,stream>>>(vals, wcombT, out, 8192, 1024, 1024, 1);
}

// Round 3
// 365.099 us; speedup vs baseline: 1.0275x; 1.0079x over previous
//
#include <hip/hip_runtime.h>
#include <stdint.h>

// NeuralMemory (Titans-style) for MI355X / gfx950.
//  norms -> kv/q GEMMs -> per-chunk MLP grads (occupancy-optimized, ping-pong
//  K-split outer products, 33KB LDS) -> double linear scan (bf16, f32 state) ->
//  retrieval (register W=w+U) -> combine GEMM. Shift-by-63 via natural indexing.

#define SEQ 4096
#define NTOK 8192

typedef unsigned short u16;
typedef __attribute__((ext_vector_type(8))) short short8;
typedef __attribute__((ext_vector_type(4))) float f32x4;
typedef __attribute__((ext_vector_type(2))) unsigned int u32x2;

__device__ __forceinline__ u16 f2b(float f) {
  union { float f; uint32_t u; } c; c.f = f;
  uint32_t u = c.u;
  uint32_t r = (u + 0x7fffu + ((u >> 16) & 1u)) >> 16;
  return (u16)r;
}
__device__ __forceinline__ float b2f(u16 h) {
  union { uint32_t u; float f; } c; c.u = ((uint32_t)h) << 16;
  return c.f;
}
__device__ __forceinline__ float sigm(float x) { return 1.f / (1.f + __expf(-x)); }
__device__ __forceinline__ uint32_t pk2(float a, float b) {
  return (uint32_t)f2b(a) | ((uint32_t)f2b(b) << 16);
}

// XOR-swizzled element index inside a [rows][128] bf16 LDS tile (16B-granule swizzle)
__device__ __forceinline__ int sidx(int r, int c) {
  return r*128 + ((((c>>3) ^ (r&7))<<3) | (c&7));
}
// contiguous 8-bf16 fragment from row-major [.][128] tile
__device__ __forceinline__ short8 frag_row_lds128(const u16* buf, int row, int ks, int l4) {
  int g = ks*4 + l4;
  return *(const short8*)&buf[row*128 + ((g ^ (row&7))<<3)];
}
// ---- OP tiles: [dim=128][k=32], 8-granule XOR swizzle ----
__device__ __forceinline__ int swzOP(int dim, int k) {
  return dim*32 + (((k>>3) ^ (dim&3))<<3) + (k&7);
}
// write 4 consecutive-k bf16 (k0 % 4 == 0, within one 8-group) from 2 packed u32
__device__ __forceinline__ void opw4(u16* tb, int dim, int k0, uint32_t p0, uint32_t p1) {
  u32x2 v; v[0] = p0; v[1] = p1;
  *(u32x2*)&tb[swzOP(dim, k0)] = v;
}
// A/B fragment read: lane dim row, k = l4*8..+7 contiguous
__device__ __forceinline__ short8 opfrag(const u16* tb, int dim, int l4) {
  return *(const short8*)&tb[dim*32 + ((l4 ^ (dim&3))<<3)];
}

// ---------------- weight prep ----------------

__global__ __launch_bounds__(256) void transpose_bf16(
    const float* __restrict__ src, u16* __restrict__ dst, int R, int C)
{
  __shared__ u16 tile[64*66];
  int tiles_x = C >> 6;
  int tx = blockIdx.x % tiles_x, ty = blockIdx.x / tiles_x;
  int c0 = tx*64, r0 = ty*64;
#pragma unroll
  for (int it=0; it<16; ++it) {
    int idx = it*256 + threadIdx.x;
    int rr = idx>>6, cc = idx&63;
    tile[cc*66 + rr] = f2b(src[(size_t)(r0+rr)*C + c0+cc]);
  }
  __syncthreads();
#pragma unroll
  for (int it=0; it<16; ++it) {
    int idx = it*256 + threadIdx.x;
    int rr = idx>>6, cc = idx&63;
    dst[(size_t)(c0+rr)*R + r0+cc] = tile[rr*66 + cc];
  }
}

__global__ __launch_bounds__(256) void smallprep(
    const float* __restrict__ w0, const float* __restrict__ w1,
    u16* __restrict__ w0T, u16* __restrict__ w1b, u16* __restrict__ w1T)
{
  int id = blockIdx.x*256 + threadIdx.x;   // 0..16383
  int i = id>>7, j = id&127;
  float a = w0[id], b = w1[id];
  w1b[id] = f2b(b);
  w0T[j*128+i] = f2b(a); w1T[j*128+i] = f2b(b);
}

// ---------------- norms + per-token gates ----------------

__global__ __launch_bounds__(256) void norms_kernel(
    const float* __restrict__ seq, const float* __restrict__ gs,
    const float* __restrict__ gr, const float* __restrict__ wstep,
    const float* __restrict__ wgate, u16* __restrict__ ss,
    u16* __restrict__ sr, float* __restrict__ lr, float* __restrict__ gate)
{
  int t = blockIdx.x; int b = t>>12, pos = t&4095;
  int tid = threadIdx.x;
  const float* row = seq + (size_t)t*1024;
  float x[4]; float ssq = 0.f;
#pragma unroll
  for (int i=0;i<4;++i){ x[i]=row[i*256+tid]; ssq += x[i]*x[i]; }
  for (int m=32;m;m>>=1) ssq += __shfl_xor(ssq, m);
  __shared__ float red[4];
  __shared__ float r2[4][16];
  int wv = tid>>6;
  if ((tid&63)==0) red[wv] = ssq;
  __syncthreads();
  float tot = red[0]+red[1]+red[2]+red[3];
  float inv = rsqrtf(tot*(1.f/1024.f) + 1e-6f);
  float ps[8], pg[8];
#pragma unroll
  for (int h=0;h<8;++h){ ps[h]=0.f; pg[h]=0.f; }
#pragma unroll
  for (int i=0;i<4;++i) {
    int d = i*256+tid;
    float sv = x[i]*inv*gs[d];
    float rv = x[i]*inv*gr[d];
    ss[(size_t)t*1024+d] = f2b(sv);
    sr[(size_t)t*1024+d] = f2b(rv);
#pragma unroll
    for (int h=0;h<8;++h) { ps[h] += sv*wstep[d*8+h]; pg[h] += rv*wgate[d*8+h]; }
  }
#pragma unroll
  for (int h=0;h<8;++h)
    for (int m=32;m;m>>=1){ ps[h] += __shfl_xor(ps[h],m); pg[h] += __shfl_xor(pg[h],m); }
  if ((tid&63)==0) {
#pragma unroll
    for (int h=0;h<8;++h){ r2[wv][h]=ps[h]; r2[wv][8+h]=pg[h]; }
  }
  __syncthreads();
  if (tid < 16) {
    float s = r2[0][tid]+r2[1][tid]+r2[2][tid]+r2[3][tid];
    float sg = sigm(s);
    if (tid<8) lr[((size_t)(b*8+tid))*4096 + pos] = sg*0.01f;
    else gate[((size_t)(b*8+(tid-8)))*4096 + pos] = sg;
  }
}

// ---------------- per-chunk gates from cmean ----------------

__global__ __launch_bounds__(256) void chunkgates_kernel(
    const u16* __restrict__ ss, const float* __restrict__ wmom,
    const float* __restrict__ wdec, float* __restrict__ mg,
    float* __restrict__ d1m)
{
  int bc = blockIdx.x; int b = bc>>6, ch = bc&63;
  size_t t0 = (size_t)(b*4096 + ch*64)*1024;
  int tid = threadIdx.x;
  float cm[4]; cm[0]=cm[1]=cm[2]=cm[3]=0.f;
  for (int tok=0; tok<64; ++tok) {
#pragma unroll
    for (int i=0;i<4;++i)
      cm[i] += b2f(ss[t0 + (size_t)tok*1024 + i*256 + tid]);
  }
  float pm[8], pd[8];
#pragma unroll
  for (int h=0;h<8;++h){ pm[h]=0.f; pd[h]=0.f; }
#pragma unroll
  for (int i=0;i<4;++i) {
    float v = cm[i]*(1.f/64.f);
    int d = i*256+tid;
#pragma unroll
    for (int h=0;h<8;++h){ pm[h]+=v*wmom[d*8+h]; pd[h]+=v*wdec[d*8+h]; }
  }
#pragma unroll
  for (int h=0;h<8;++h)
    for (int m=32;m;m>>=1){ pm[h] += __shfl_xor(pm[h],m); pd[h] += __shfl_xor(pd[h],m); }
  __shared__ float r2[4][16];
  int wv = tid>>6;
  if ((tid&63)==0) {
#pragma unroll
    for (int h=0;h<8;++h){ r2[wv][h]=pm[h]; r2[wv][8+h]=pd[h]; }
  }
  __syncthreads();
  if (tid < 16) {
    float s = r2[0][tid]+r2[1][tid]+r2[2][tid]+r2[3][tid];
    if (tid<8) mg[(b*8+tid)*64 + ch] = sigm(s);
    else d1m[(b*8+(tid-8))*64 + ch] = 1.f - sigm(s);
  }
}

// ---------------- generic bf16 GEMM: C = A(MxK) @ Bt(NxK)^T ----------------

__global__ __launch_bounds__(256) void gemm_bt(
    const u16* __restrict__ A, const u16* __restrict__ Bt,
    void* __restrict__ C, int M, int N, int K, int out_f32)
{
  __shared__ __align__(16) u16 As[128*64];
  __shared__ __align__(16) u16 Bs[128*64];
  int tid = threadIdx.x;
  int wv = tid>>6, lane = tid&63;
  int wr = wv>>1, wc = wv&1;
  int l15 = lane&15, l4 = lane>>4;
  // XCD-aware bijective block swizzle (grid sizes here are all %8==0)
  int nwg = gridDim.x*gridDim.y;
  int wg  = blockIdx.y*gridDim.x + blockIdx.x;
  int cpx = nwg >> 3;
  int swz = (wg & 7)*cpx + (wg >> 3);
  int bx = swz % gridDim.x, by = swz / gridDim.x;
  int brow = by*128, bcol = bx*128;
  f32x4 acc[4][4] = {};
  for (int kt=0; kt<K; kt+=64) {
#pragma unroll
    for (int it=0; it<4; ++it) {
      int gi = it*256 + tid;
      int row = gi>>3, g = gi&7;
      int sg = g ^ (row&7);
      *(short8*)&As[row*64 + sg*8] = *(const short8*)&A[(size_t)(brow+row)*K + kt + g*8];
      *(short8*)&Bs[row*64 + sg*8] = *(const short8*)&Bt[(size_t)(bcol+row)*K + kt + g*8];
    }
    __syncthreads();
#pragma unroll
    for (int ks=0; ks<2; ++ks) {
      short8 af[4], bfr[4];
#pragma unroll
      for (int m=0;m<4;++m) {
        int row = wr*64 + m*16 + l15;
        int g = ks*4 + l4;
        af[m] = *(const short8*)&As[row*64 + ((g ^ (row&7))<<3)];
      }
#pragma unroll
      for (int n=0;n<4;++n) {
        int row = wc*64 + n*16 + l15;
        int g = ks*4 + l4;
        bfr[n] = *(const short8*)&Bs[row*64 + ((g ^ (row&7))<<3)];
      }
#pragma unroll
      for (int m=0;m<4;++m)
#pragma unroll
        for (int n=0;n<4;++n)
          acc[m][n] = __builtin_amdgcn_mfma_f32_16x16x32_bf16(af[m], bfr[n], acc[m][n], 0,0,0);
    }
    __syncthreads();
  }
#pragma unroll
  for (int m=0;m<4;++m) {
#pragma unroll
    for (int n=0;n<4;++n) {
      int col = bcol + wc*64 + n*16 + l15;
#pragma unroll
      for (int j=0;j<4;++j) {
        int row = brow + wr*64 + m*16 + l4*4 + j;
        if (out_f32) ((float*)C)[(size_t)row*N + col] = acc[m][n][j];
        else ((u16*)C)[(size_t)row*N + col] = f2b(acc[m][n][j]);
      }
    }
  }
}

// ---------------- per-chunk MLP gradients -> transposed bf16 surprise ----------------
// loss = sum_r lr[r]*mean_e(pred-v)^2 ; pred = silu(k@w0)@w1
// S0T = -(dx1^T @ k) ; S1T = -(dpred^T @ a)
// LDS: bufK (K rows -> a rows -> tile T0), bufV (V rows -> dpred rows -> tile T1).
// Tile = A-part [128][32] (DlT or DXT) + B-part [128][32] (AlT or KtT).
// K-dim (64 chunk rows) split in two 32-halves ping-ponged T0/T1.

__global__ __launch_bounds__(256,3) void grad_kernel(
    const u16* __restrict__ kvout, const float* __restrict__ lr,
    const u16* __restrict__ w0T, const u16* __restrict__ w1T,
    const u16* __restrict__ w1b, u16* __restrict__ S)
{
  __shared__ __align__(16) u16 bufK[64*128];
  __shared__ __align__(16) u16 bufV[64*128];
  __shared__ float lr_s[64];
  int bid = blockIdx.x;
  int bh = bid>>6, ch = bid&63;
  int b = bh>>3, hh = bh&7;
  int tid = threadIdx.x;
  int w = tid>>6, lane = tid&63;
  int l15 = lane&15, l4 = lane>>4;
  size_t t0 = (size_t)(b*4096 + ch*64);

  // stage K rows -> bufK, V rows -> bufV (coalesced b128, sidx swizzle)
#pragma unroll
  for (int it=0; it<4; ++it) {
    int gi = it*256 + tid;
    int row = gi>>4, g = gi&15;
    int sg = g ^ (row&7);
    *(short8*)&bufK[row*128 + sg*8] = *(const short8*)&kvout[(t0+row)*2048 + hh*128 + g*8];
    *(short8*)&bufV[row*128 + sg*8] = *(const short8*)&kvout[(t0+row)*2048 + 1024 + hh*128 + g*8];
  }
  if (tid < 64) lr_s[tid] = lr[(size_t)bh*4096 + ch*64 + tid];
  __syncthreads();   // B1

  // x1 = k @ w0 (wave w owns rows w*16..+15)
  f32x4 x1[8] = {};
#pragma unroll
  for (int ks=0; ks<4; ++ks) {
    short8 af = frag_row_lds128(bufK, w*16 + l15, ks, l4);
    int kof = ks*32 + l4*8;
#pragma unroll
    for (int n=0;n<8;++n) {
      short8 bf = *(const short8*)&w0T[(size_t)(n*16+l15)*128 + kof];
      x1[n] = __builtin_amdgcn_mfma_f32_16x16x32_bf16(af, bf, x1[n], 0,0,0);
    }
  }
  int r0 = w*16 + l4*4;
  // a = silu(x1): rows into bufK (own rows, k no longer needed there) + packed regs
  uint32_t a_pk[16];
#pragma unroll
  for (int n=0;n<8;++n) {
    int c = n*16 + l15;
    float av[4];
#pragma unroll
    for (int j=0;j<4;++j) { float xv = x1[n][j]; av[j] = xv*sigm(xv); }
    bufK[sidx(r0+0,c)] = f2b(av[0]);
    bufK[sidx(r0+1,c)] = f2b(av[1]);
    bufK[sidx(r0+2,c)] = f2b(av[2]);
    bufK[sidx(r0+3,c)] = f2b(av[3]);
    a_pk[n*2]   = pk2(av[0], av[1]);
    a_pk[n*2+1] = pk2(av[2], av[3]);
  }
  // pred = a @ w1 (own rows of bufK)
  f32x4 pr[8] = {};
#pragma unroll
  for (int ks=0; ks<4; ++ks) {
    short8 af = frag_row_lds128(bufK, w*16 + l15, ks, l4);
    int kof = ks*32 + l4*8;
#pragma unroll
    for (int n=0;n<8;++n) {
      short8 bf = *(const short8*)&w1T[(size_t)(n*16+l15)*128 + kof];
      pr[n] = __builtin_amdgcn_mfma_f32_16x16x32_bf16(af, bf, pr[n], 0,0,0);
    }
  }
  // dpred = (2/128)*lr*(pred - v): read V (own rows), write Dl rows into bufV, pack
  uint32_t dp_pk[16];
#pragma unroll
  for (int n=0;n<8;++n) {
    int c = n*16 + l15;
    float dv[4];
#pragma unroll
    for (int j=0;j<4;++j)
      dv[j] = 0.015625f * lr_s[r0+j] * (pr[n][j] - b2f(bufV[sidx(r0+j,c)]));
    bufV[sidx(r0+0,c)] = f2b(dv[0]);
    bufV[sidx(r0+1,c)] = f2b(dv[1]);
    bufV[sidx(r0+2,c)] = f2b(dv[2]);
    bufV[sidx(r0+3,c)] = f2b(dv[3]);
    dp_pk[n*2]   = pk2(dv[0], dv[1]);
    dp_pk[n*2+1] = pk2(dv[2], dv[3]);
  }
  // da = dpred @ w1^T (own rows of bufV)
  f32x4 da[8] = {};
#pragma unroll
  for (int ks=0; ks<4; ++ks) {
    short8 af = frag_row_lds128(bufV, w*16 + l15, ks, l4);
    int kof = ks*32 + l4*8;
#pragma unroll
    for (int n=0;n<8;++n) {
      short8 bf = *(const short8*)&w1b[(size_t)(n*16+l15)*128 + kof];
      da[n] = __builtin_amdgcn_mfma_f32_16x16x32_bf16(af, bf, da[n], 0,0,0);
    }
  }
  // dx1 = da * silu'(x1) -> packed regs
  uint32_t dx_pk[16];
#pragma unroll
  for (int n=0;n<8;++n) {
    float d[4];
#pragma unroll
    for (int j=0;j<4;++j) {
      float xv = x1[n][j];
      float sg = sigm(xv);
      d[j] = da[n][j]*(sg*(1.f + xv*(1.f - sg)));
    }
    dx_pk[n*2]   = pk2(d[0], d[1]);
    dx_pk[n*2+1] = pk2(d[2], d[3]);
  }
  __syncthreads();   // B2: all row-phase LDS reads done; bufK/bufV freed for tiles

  u16* T0 = bufK;          // A-part [0..4095], B-part [4096..8191]
  u16* T1 = bufV;
  int klo = r0 & 31;       // this wave's k-columns within a 32-half
  f32x4 g1[2][8] = {};

  // P1: waves 0,1 write DlT+AlT half0 -> T0
  if (w < 2) {
#pragma unroll
    for (int n=0;n<8;++n) {
      int c = n*16 + l15;
      opw4(T0,      c, klo, dp_pk[n*2], dp_pk[n*2+1]);
      opw4(T0+4096, c, klo, a_pk[n*2],  a_pk[n*2+1]);
    }
  }
  __syncthreads();   // B3

  // P2: mfma g1 += half0 (T0); waves 2,3 write half1 -> T1
  if (w >= 2) {
#pragma unroll
    for (int n=0;n<8;++n) {
      int c = n*16 + l15;
      opw4(T1,      c, klo, dp_pk[n*2], dp_pk[n*2+1]);
      opw4(T1+4096, c, klo, a_pk[n*2],  a_pk[n*2+1]);
    }
  }
#pragma unroll
  for (int n=0;n<8;++n) {
    short8 bf = opfrag(T0+4096, n*16 + l15, l4);
#pragma unroll
    for (int mi=0;mi<2;++mi) {
      short8 af = opfrag(T0, w*32 + mi*16 + l15, l4);
      g1[mi][n] = __builtin_amdgcn_mfma_f32_16x16x32_bf16(af, bf, g1[mi][n], 0,0,0);
    }
  }
  __syncthreads();   // B4

  // P3: mfma g1 += half1 (T1); OP2 half0 writes -> T0 (DXT by w01, KtT by w23);
  //     then store S1.
  if (w < 2) {
#pragma unroll
    for (int n=0;n<8;++n)
      opw4(T0, n*16 + l15, klo, dx_pk[n*2], dx_pk[n*2+1]);
  } else {
    int idx = (w-2)*64 + lane;          // 0..127
    int rl = idx>>2;                    // 0..31 (half0 row)
    int in0 = (idx&3)*32;
#pragma unroll
    for (int g4=0; g4<4; ++g4) {
      short8 kr = *(const short8*)&kvout[(t0+rl)*2048 + hh*128 + in0 + g4*8];
#pragma unroll
      for (int i=0;i<8;++i)
        T0[4096 + swzOP(in0+g4*8+i, rl)] = (u16)(short)kr[i];
    }
  }
#pragma unroll
  for (int n=0;n<8;++n) {
    short8 bf = opfrag(T1+4096, n*16 + l15, l4);
#pragma unroll
    for (int mi=0;mi<2;++mi) {
      short8 af = opfrag(T1, w*32 + mi*16 + l15, l4);
      g1[mi][n] = __builtin_amdgcn_mfma_f32_16x16x32_bf16(af, bf, g1[mi][n], 0,0,0);
    }
  }
  {
    u16* S1 = S + ((size_t)(16+bh)*64 + ch)*16384;
#pragma unroll
    for (int mi=0;mi<2;++mi)
#pragma unroll
      for (int n=0;n<8;++n)
#pragma unroll
        for (int j=0;j<4;++j) {
          int m = w*32 + mi*16 + l4*4 + j, c = n*16 + l15;
          S1[m*128 + c] = f2b(-g1[mi][n][j]);
        }
  }
  __syncthreads();   // B5

  // P4: mfma g0 += half0 (T0); OP2 half1 writes -> T1 (DXT by w23, KtT by w01)
  f32x4 g0[2][8] = {};
  if (w >= 2) {
#pragma unroll
    for (int n=0;n<8;++n)
      opw4(T1, n*16 + l15, klo, dx_pk[n*2], dx_pk[n*2+1]);
  } else {
    int idx = w*64 + lane;              // 0..127
    int rl = idx>>2;
    int in0 = (idx&3)*32;
#pragma unroll
    for (int g4=0; g4<4; ++g4) {
      short8 kr = *(const short8*)&kvout[(t0+32+rl)*2048 + hh*128 + in0 + g4*8];
#pragma unroll
      for (int i=0;i<8;++i)
        T1[4096 + swzOP(in0+g4*8+i, rl)] = (u16)(short)kr[i];
    }
  }
#pragma unroll
  for (int n=0;n<8;++n) {
    short8 bf = opfrag(T0+4096, n*16 + l15, l4);
#pragma unroll
    for (int mi=0;mi<2;++mi) {
      short8 af = opfrag(T0, w*32 + mi*16 + l15, l4);
      g0[mi][n] = __builtin_amdgcn_mfma_f32_16x16x32_bf16(af, bf, g0[mi][n], 0,0,0);
    }
  }
  __syncthreads();   // B6

  // P5: mfma g0 += half1 (T1); store S0
#pragma unroll
  for (int n=0;n<8;++n) {
    short8 bf = opfrag(T1+4096, n*16 + l15, l4);
#pragma unroll
    for (int mi=0;mi<2;++mi) {
      short8 af = opfrag(T1, w*32 + mi*16 + l15, l4);
      g0[mi][n] = __builtin_amdgcn_mfma_f32_16x16x32_bf16(af, bf, g0[mi][n], 0,0,0);
    }
  }
  {
    u16* S0 = S + ((size_t)bh*64 + ch)*16384;
#pragma unroll
    for (int mi=0;mi<2;++mi)
#pragma unroll
      for (int n=0;n<8;++n)
#pragma unroll
        for (int j=0;j<4;++j) {
          int m = w*32 + mi*16 + l4*4 + j, c = n*16 + l15;
          S0[m*128 + c] = f2b(-g0[mi][n][j]);
        }
  }
}

// ---------------- double linear-recurrence scan over chunks (in place, bf16) ----------------

__global__ __launch_bounds__(256) void scan_kernel(
    u16* __restrict__ S, const float* __restrict__ mg, const float* __restrict__ d1m)
{
  int bidx = blockIdx.x;              // (m*16+bh)*64 + eblk
  int eblk = bidx & 63;
  int mbh = bidx >> 6;                // 0..31
  int bh = mbh & 15;
  int e = eblk*256 + threadIdx.x;
  u16* base = S + (size_t)mbh*64*16384 + e;
  const float* g1 = mg + bh*64;
  const float* g2 = d1m + bh*64;
  float mom = 0.f, upd = 0.f;
  for (int c2=0; c2<64; ++c2) {
    float s = b2f(base[(size_t)c2*16384]);
    mom = g1[c2]*mom + s;            // momentum scan
    upd = g2[c2]*upd + mom;          // update scan
    base[(size_t)c2*16384] = f2b(upd);
  }
}

// ---------------- per-chunk retrieval (W = w + U summed in registers) ----------------

__global__ __launch_bounds__(256) void retrieve_kernel(
    const u16* __restrict__ qn, const u16* __restrict__ U,
    const u16* __restrict__ w0T, const u16* __restrict__ w1T,
    const float* __restrict__ gamma, const float* __restrict__ gate,
    u16* __restrict__ vals)
{
  __shared__ __align__(16) u16 QA[64*128];    // Q tile, later reused for silu(x)
  int bid = blockIdx.x; int bh = bid>>6, ch = bid&63;
  int b = bh>>3, h = bh&7;
  int tid = threadIdx.x;
  int w = tid>>6, lane = tid&63;
  int l15 = lane&15, l4 = lane>>4;
  const u16* U0 = U + ((size_t)bh*64 + ch)*16384;
  const u16* U1 = U + ((size_t)(16+bh)*64 + ch)*16384;
#pragma unroll
  for (int it=0; it<4; ++it) {
    int gi = it*256 + tid; int row = gi>>4, g = gi&15;
    int posn = ch*64 + row + 63;       // natural position of shifted query row
    short8 v;
    if (posn < 4096) v = *(const short8*)&qn[((size_t)(b*4096+posn))*1024 + h*128 + g*8];
    else {
#pragma unroll
      for (int i=0;i<8;++i) v[i]=0;
    }
    *(short8*)&QA[row*128 + ((g ^ (row&7))<<3)] = v;
  }
  __syncthreads();
  // x = q @ (w0+u0): B-fragments built in registers from bf16 w0T + U0T
  f32x4 xx[8] = {};
#pragma unroll
  for (int ks=0; ks<4; ++ks) {
    short8 af = frag_row_lds128(QA, w*16 + l15, ks, l4);
    int kof = ks*32 + l4*8;
#pragma unroll
    for (int n=0;n<8;++n) {
      size_t o = (size_t)(n*16+l15)*128 + kof;
      short8 wa = *(const short8*)&w0T[o];
      short8 ua = *(const short8*)&U0[o];
      short8 bf;
#pragma unroll
      for (int i=0;i<8;++i) bf[i] = (short)f2b(b2f((u16)(short)wa[i]) + b2f((u16)(short)ua[i]));
      xx[n] = __builtin_amdgcn_mfma_f32_16x16x32_bf16(af, bf, xx[n], 0,0,0);
    }
  }
  // silu(x) overwrites own rows of QA
  int r0 = w*16 + l4*4;
#pragma unroll
  for (int n=0;n<8;++n) {
    int c = n*16 + l15;
#pragma unroll
    for (int j=0;j<4;++j) {
      float xv = xx[n][j];
      QA[sidx(r0+j,c)] = f2b(xv * sigm(xv));
    }
  }
  // vals = silu(x) @ (w1+u1)
  f32x4 vv[8] = {};
#pragma unroll
  for (int ks=0; ks<4; ++ks) {
    short8 af = frag_row_lds128(QA, w*16 + l15, ks, l4);
    int kof = ks*32 + l4*8;
#pragma unroll
    for (int n=0;n<8;++n) {
      size_t o = (size_t)(n*16+l15)*128 + kof;
      short8 wa = *(const short8*)&w1T[o];
      short8 ua = *(const short8*)&U1[o];
      short8 bf;
#pragma unroll
      for (int i=0;i<8;++i) bf[i] = (short)f2b(b2f((u16)(short)wa[i]) + b2f((u16)(short)ua[i]));
      vv[n] = __builtin_amdgcn_mfma_f32_16x16x32_bf16(af, bf, vv[n], 0,0,0);
    }
  }
  // epilogue: rmsnorm over dh, *(1+gamma), *gate, store at natural pos
#pragma unroll
  for (int j=0;j<4;++j) {
    float ssq = 0.f;
#pragma unroll
    for (int n=0;n<8;++n) ssq += vv[n][j]*vv[n][j];
    ssq += __shfl_xor(ssq,1); ssq += __shfl_xor(ssq,2);
    ssq += __shfl_xor(ssq,4); ssq += __shfl_xor(ssq,8);
    float rms = rsqrtf(ssq*(1.f/128.f) + 1e-6f);
    int r = r0 + j;
    int posn = ch*64 + r + 63;
    if (posn < 4096) {
      float gt = gate[(size_t)bh*4096 + posn];
      size_t orow = ((size_t)(b*4096+posn))*1024 + h*128;
#pragma unroll
      for (int n=0;n<8;++n) {
        int c = n*16 + l15;
        vals[orow + c] = f2b(vv[n][j]*rms*(1.f + gamma[h*128+c])*gt);
      }
    }
  }
}

extern "C" void kernel_launch(void* const* d_in, const int* in_sizes, int n_in,
                              void* d_out, int out_size, void* d_ws, size_t ws_size,
                              hipStream_t stream) {
  const float* seq    = (const float*)d_in[0];
  const float* gstore = (const float*)d_in[1];
  const float* gret   = (const float*)d_in[2];
  const float* wkv    = (const float*)d_in[3];
  const float* wq     = (const float*)d_in[4];
  const float* wstep  = (const float*)d_in[5];
  const float* wmom   = (const float*)d_in[6];
  const float* wdec   = (const float*)d_in[7];
  const float* wgate  = (const float*)d_in[8];
  const float* wcomb  = (const float*)d_in[9];
  const float* gamma  = (const float*)d_in[10];
  const float* w0f    = (const float*)d_in[11];
  const float* w1f    = (const float*)d_in[12];
  float* out = (float*)d_out;
  (void)in_sizes; (void)n_in; (void)out_size; (void)ws_size;

  char* p = (char*)d_ws;
  size_t off = 0;
  auto alloc = [&](size_t bytes) -> void* {
    void* r = p + off; off += (bytes + 255) & ~(size_t)255; return r;
  };
  u16* wkvT   = (u16*)alloc((size_t)2048*1024*2);
  u16* wqT    = (u16*)alloc((size_t)1024*1024*2);
  u16* wcombT = (u16*)alloc((size_t)1024*1024*2);
  u16* w0T    = (u16*)alloc(16384*2);
  u16* w1b    = (u16*)alloc(16384*2);
  u16* w1T    = (u16*)alloc(16384*2);
  u16* ss     = (u16*)alloc((size_t)NTOK*1024*2);
  u16* sr     = (u16*)alloc((size_t)NTOK*1024*2);
  u16* kvout  = (u16*)alloc((size_t)NTOK*2048*2);
  u16* qn     = (u16*)alloc((size_t)NTOK*1024*2);
  u16* vals   = (u16*)alloc((size_t)NTOK*1024*2);
  float* lr   = (float*)alloc((size_t)16*4096*4);
  float* gate = (float*)alloc((size_t)16*4096*4);
  float* mg   = (float*)alloc(1024*4);
  float* d1m  = (float*)alloc(1024*4);
  u16* S      = (u16*)alloc((size_t)32*64*16384*2);

  transpose_bf16<<<dim3(512),dim3(256),0,stream>>>(wkv, wkvT, 1024, 2048);
  transpose_bf16<<<dim3(256),dim3(256),0,stream>>>(wq, wqT, 1024, 1024);
  transpose_bf16<<<dim3(256),dim3(256),0,stream>>>(wcomb, wcombT, 1024, 1024);
  smallprep<<<dim3(64),dim3(256),0,stream>>>(w0f, w1f, w0T, w1b, w1T);
  norms_kernel<<<dim3(NTOK),dim3(256),0,stream>>>(seq, gstore, gret, wstep, wgate, ss, sr, lr, gate);
  chunkgates_kernel<<<dim3(128),dim3(256),0,stream>>>(ss, wmom, wdec, mg, d1m);
  gemm_bt<<<dim3(16,64),dim3(256),0,stream>>>(ss, wkvT, kvout, 8192, 2048, 1024, 0);
  gemm_bt<<<dim3(8,64),dim3(256),0,stream>>>(sr, wqT, qn, 8192, 1024, 1024, 0);
  grad_kernel<<<dim3(1024),dim3(256),0,stream>>>(kvout, lr, w0T, w1T, w1b, S);
  scan_kernel<<<dim3(2048),dim3(256),0,stream>>>(S, mg, d1m);
  hipMemsetAsync(vals, 0, (size_t)NTOK*1024*2, stream);
  retrieve_kernel<<<dim3(1024),dim3(256),0,stream>>>(qn, S, w0T, w1T, gamma, gate, vals);
  gemm_bt<<<dim3(8,64),dim3(256),0,stream>>>(vals, wcombT, out, 8192, 1024, 1024, 1);
}